// Round 10
// baseline (853.232 us; speedup 1.0000x reference)
//
#include <hip/hip_runtime.h>
#include <hip/hip_bf16.h>

// Problem constants (StaticRecurrentEntNet): B=256,S=32,L=32,D=256,E=64,VOCAB=50000
#define Bb 256
#define Ss 32
#define Ll 32
#define Dd 256
#define Ee 64

typedef __attribute__((ext_vector_type(8))) short short8v;
typedef __attribute__((ext_vector_type(4))) float float4v;

static __device__ __forceinline__ unsigned short f2bf(float f) {
    unsigned int x = __float_as_uint(f);
    return (unsigned short)((x + 0x7fffu + ((x >> 16) & 1u)) >> 16);   // RNE
}
static __device__ __forceinline__ unsigned int pk2(float a, float b) {
    return (unsigned int)f2bf(a) | ((unsigned int)f2bf(b) << 16);
}

// ---------------- Kernel A: enc[bs][d] = sum_l emb[tok[bs][l]][d]*mask[bs][l]; active[bs]
__global__ void k_enc(const int* __restrict__ tok, const float* __restrict__ mask,
                      const float* __restrict__ emb, float* __restrict__ enc,
                      int* __restrict__ act) {
    int bs = blockIdx.x;            // 0..B*S-1
    int d  = threadIdx.x;           // 0..255
    const int*   t = tok  + (long)bs * Ll;
    const float* m = mask + (long)bs * Ll;
    float acc = 0.f;
    #pragma unroll 4
    for (int l = 0; l < Ll; ++l) {
        acc += emb[(long)t[l] * Dd + d] * m[l];
    }
    enc[(long)bs * Dd + d] = acc;
    if (d == 0) {
        float s = 0.f;
        for (int l = 0; l < Ll; ++l) s += m[l];
        act[bs] = (s > 0.f) ? 1 : 0;
    }
}

// ---------------- Kernel B: Y[rows][256] = X[rows][256] @ M[256][256]  (fp32)
// 16 rows per block (round-2-proven variant).
__global__ void k_rowmat(const float* __restrict__ X, const float* __restrict__ M,
                         float* __restrict__ Y) {
    __shared__ __align__(16) float xs[16 * Dd];
    int tid = threadIdx.x;
    long row0 = (long)blockIdx.x * 16;
    #pragma unroll
    for (int i = 0; i < 16; ++i) xs[i * Dd + tid] = X[(row0 + i) * Dd + tid];
    __syncthreads();
    int cg = tid & 63;   // cols cg*4 .. +3
    int rq = tid >> 6;   // rows rq*4 .. +3
    float acc[4][4];
    #pragma unroll
    for (int r = 0; r < 4; ++r)
        #pragma unroll
        for (int c = 0; c < 4; ++c) acc[r][c] = 0.f;
    for (int d = 0; d < Dd; ++d) {
        float4 mv = *reinterpret_cast<const float4*>(&M[d * Dd + cg * 4]);
        #pragma unroll
        for (int r = 0; r < 4; ++r) {
            float x = xs[(rq * 4 + r) * Dd + d];
            acc[r][0] += x * mv.x; acc[r][1] += x * mv.y;
            acc[r][2] += x * mv.z; acc[r][3] += x * mv.w;
        }
    }
    #pragma unroll
    for (int r = 0; r < 4; ++r) {
        float4 o = make_float4(acc[r][0], acc[r][1], acc[r][2], acc[r][3]);
        *reinterpret_cast<float4*>(&Y[(row0 + rq * 4 + r) * Dd + cg * 4]) = o;
    }
}

// ---------------- Kernel Bgk v2: gk[b*32+s][e] = dot(enc[b][s], keys[b][e])
// One block per b. keys_b staged once in swizzled LDS (reused by all 32 s).
__global__ __launch_bounds__(256) void k_gk(const float* __restrict__ enc,
                                            const float* __restrict__ keys,
                                            float* __restrict__ gk) {
    __shared__ __align__(16) char kls[Ee * 1024];      // keys_b fp32, swizzled, 64KB
    __shared__ __align__(16) float es[Ss * Dd];        // enc_b, 32KB
    const int tid = threadIdx.x;
    const int b   = blockIdx.x;
    {
        const float4* kg = reinterpret_cast<const float4*>(keys + (long)b * Ee * Dd);
        #pragma unroll
        for (int i = 0; i < 16; ++i) {
            const int idx = tid + 256 * i;             // f4 unit, 0..4095
            const int e   = idx >> 6;
            const int d4  = idx & 63;
            *reinterpret_cast<float4*>(kls + (((e << 10) + (d4 << 4)) ^ ((e & 7) << 4)))
                = kg[idx];
        }
        const float4* eg = reinterpret_cast<const float4*>(enc + (long)b * Ss * Dd);
        float4* es4 = reinterpret_cast<float4*>(es);
        #pragma unroll
        for (int i = 0; i < 8; ++i) es4[tid + 256 * i] = eg[tid + 256 * i];
    }
    __syncthreads();
    const int w = tid >> 6;        // wave: s in [w*8, w*8+8)
    const int e = tid & 63;
    float acc[8];
    #pragma unroll
    for (int i = 0; i < 8; ++i) acc[i] = 0.f;
    const char* krow = kls;
    for (int d4 = 0; d4 < 64; ++d4) {
        const float4 kvf = *reinterpret_cast<const float4*>(
            krow + (((e << 10) + (d4 << 4)) ^ ((e & 7) << 4)));
        #pragma unroll
        for (int i = 0; i < 8; ++i) {
            const float4 ev = *reinterpret_cast<const float4*>(&es[(w * 8 + i) * Dd + d4 * 4]);
            acc[i] += ev.x * kvf.x + ev.y * kvf.y + ev.z * kvf.z + ev.w * kvf.w;
        }
    }
    #pragma unroll
    for (int i = 0; i < 8; ++i)
        gk[((long)b * Ss + w * 8 + i) * Ee + e] = acc[i];
}

// ---------------- Kernel Ut: Utg[c][k] = bf16(U[k][c])  (pre-transpose for A-operand)
__global__ void k_ut(const float* __restrict__ U, unsigned short* __restrict__ Utg) {
    const int c0 = blockIdx.x * 16;
    const int k  = threadIdx.x;      // 0..255
    float v[16];
    #pragma unroll
    for (int i = 0; i < 16; ++i) v[i] = U[k * Dd + c0 + i];
    #pragma unroll
    for (int i = 0; i < 16; ++i) Utg[(c0 + i) * Dd + k] = f2bf(v[i]);
}

// ---------------- Kernel D v4: 32-step recurrence, 16 waves x 16 output-cols.
// 1024 threads = 16 waves; wave w owns cols [w*16, w*16+16) for ALL 64 entities.
// A = U^T 16-col slice in regs (aU[8] = 32 VGPR); B = h from 32KB swizzled bf16
// LDS mirror. Register demand ~100-120 <= the 128-VGPR cap a 16-wave block
// naturally imposes (4 waves/SIMD co-resident) -> no spill BY CONSTRUCTION
// (rounds 7/9: 8-wave block + allocator cap 128 -> 71-86MB scratch spill).
// kv NOT register-resident (reloaded from L2 each step, hidden under GEMM).
// D-layout: col=lane&15 = e-within-tile(n), row=4q+j = c-within-slice.
// 2 barriers/step; same race-free protocol as v3 (writes post-B2, reads post-B1).
__global__ __launch_bounds__(1024, 1) void k_scan(
    const float* __restrict__ enc, const int* __restrict__ act,
    const float* __restrict__ gk,  const float* __restrict__ kv,
    const float* __restrict__ eWm, const unsigned short* __restrict__ Utg,
    float* __restrict__ out) {
    __shared__ __align__(16) unsigned short hbf[Ee * Dd];  // [e][k] bf16, swizzled, 32KB
    __shared__ float part_g[16][Ee];                       // 4KB
    __shared__ float part_rn[16][Ee];                      // 4KB

    const int tid = threadIdx.x;
    const int b   = blockIdx.x;
    const int w   = tid >> 6;       // wave id 0..15, c0 = w*16
    const int l   = tid & 63;
    const int q   = l >> 4;
    const int sl  = l & 15;
    const int c0  = w * 16;

    // ---- zero hbf + parts ----
    {
        uint4 z4 = make_uint4(0u, 0u, 0u, 0u);
        uint4* hz = reinterpret_cast<uint4*>(hbf);
        #pragma unroll
        for (int i = 0; i < 2; ++i) hz[tid + 1024 * i] = z4;
        (&part_g[0][0])[tid]  = 0.f;
        (&part_rn[0][0])[tid] = 0.f;
    }

    // ---- A-frags: U^T 16-col slice, registers for the whole kernel (32 VGPR) ----
    short8v aU[8];
    #pragma unroll
    for (int kk = 0; kk < 8; ++kk)
        aU[kk] = *reinterpret_cast<const short8v*>(
            Utg + (c0 + sl) * Dd + kk * 32 + q * 8);

    float4v h_d[4];   // h[e = n*16+sl][c = c0+q*4+j]
    #pragma unroll
    for (int n = 0; n < 4; ++n) h_d[n] = (float4v)0.f;

    const unsigned long long actmask = __ballot((l < Ss) && (act[b * Ss + l] != 0));
    const int bswz = (sl & 7) << 4;
    char* hb = reinterpret_cast<char*>(hbf);

    // es prefetch chain (wave's 16-col slice -> one float4 per lane)
    float4v esN = *reinterpret_cast<const float4v*>(
        enc + (long)(b * Ss) * Dd + c0 + q * 4);

    __syncthreads();   // hbf/part zero visible

    for (int s = 0; s < Ss; ++s) {
        const long bs = (long)b * Ss + s;
        const float4v esc = esN;
        if (s + 1 < Ss)
            esN = *reinterpret_cast<const float4v*>(
                enc + (bs + 1) * Dd + c0 + q * 4);
        if ((actmask >> s) & 1ull) {
            // gk loads (consumed after B1 — latency hidden by g-dot + barrier)
            float gkl[4];
            #pragma unroll
            for (int n = 0; n < 4; ++n) gkl[n] = gk[bs * Ee + n * 16 + sl];

            // ---- g-partials over this wave's 16 c, all 64 e ----
            #pragma unroll
            for (int n = 0; n < 4; ++n) {
                float pg = esc[0] * h_d[n][0] + esc[1] * h_d[n][1]
                         + esc[2] * h_d[n][2] + esc[3] * h_d[n][3];
                pg += __shfl_xor(pg, 16);
                pg += __shfl_xor(pg, 32);
                if (q == 0) part_g[w][n * 16 + sl] = pg;
            }
            __syncthreads();                                   // B1

            // ---- g-final (redundant per q-group; independent add chains) ----
            float g4[4];
            #pragma unroll
            for (int n = 0; n < 4; ++n) {
                const int e = n * 16 + sl;
                float x0 = part_g[0][e] + part_g[1][e] + part_g[2][e] + part_g[3][e];
                float x1 = part_g[4][e] + part_g[5][e] + part_g[6][e] + part_g[7][e];
                float x2 = part_g[8][e] + part_g[9][e] + part_g[10][e] + part_g[11][e];
                float x3 = part_g[12][e] + part_g[13][e] + part_g[14][e] + part_g[15][e];
                const float x = (x0 + x1) + (x2 + x3) + gkl[n];
                g4[n] = 1.f / (1.f + expf(-x));
            }

            // ---- GEMM: acc[n] = U^T-slice @ h^T  (A regs, B from hbf) ----
            float4v acc[4];
            #pragma unroll
            for (int n = 0; n < 4; ++n) acc[n] = (float4v)0.f;
            #pragma unroll
            for (int kk = 0; kk < 8; ++kk) {
                short8v bh[4];
                #pragma unroll
                for (int n = 0; n < 4; ++n)
                    bh[n] = *reinterpret_cast<const short8v*>(
                        hb + ((((n * 16 + sl) << 9) + (kk << 6) + (q << 4)) ^ bswz));
                #pragma unroll
                for (int n = 0; n < 4; ++n)
                    acc[n] = __builtin_amdgcn_mfma_f32_16x16x32_bf16(
                        aU[kk], bh[n], acc[n], 0, 0, 0);
            }

            // ---- epilogue: h_t = relu(acc+kv+eW); h_d += g*h_t; ss partials ----
            const float4v ewv = *reinterpret_cast<const float4v*>(
                eWm + bs * Dd + c0 + q * 4);
            float4v kvv[4];
            #pragma unroll
            for (int n = 0; n < 4; ++n)
                kvv[n] = *reinterpret_cast<const float4v*>(
                    kv + ((long)b * Ee + n * 16 + sl) * Dd + c0 + q * 4);
            float ssp[4];
            #pragma unroll
            for (int n = 0; n < 4; ++n) {
                float sp = 0.f;
                #pragma unroll
                for (int j = 0; j < 4; ++j) {
                    float ht = acc[n][j] + kvv[n][j] + ewv[j];
                    ht = fmaxf(ht, 0.f);
                    const float hn = h_d[n][j] + g4[n] * ht;
                    h_d[n][j] = hn;
                    sp += hn * hn;
                }
                ssp[n] = sp;
            }
            #pragma unroll
            for (int n = 0; n < 4; ++n) {
                ssp[n] += __shfl_xor(ssp[n], 16);
                ssp[n] += __shfl_xor(ssp[n], 32);
                if (q == 0) part_rn[w][n * 16 + sl] = ssp[n];
            }
            __syncthreads();                                   // B2

            // ---- normalize + refresh bf16 mirror ----
            #pragma unroll
            for (int n = 0; n < 4; ++n) {
                const int e = n * 16 + sl;
                float t0 = part_rn[0][e] + part_rn[1][e] + part_rn[2][e] + part_rn[3][e];
                float t1 = part_rn[4][e] + part_rn[5][e] + part_rn[6][e] + part_rn[7][e];
                float t2 = part_rn[8][e] + part_rn[9][e] + part_rn[10][e] + part_rn[11][e];
                float t3 = part_rn[12][e] + part_rn[13][e] + part_rn[14][e] + part_rn[15][e];
                const float t = (t0 + t1) + (t2 + t3);
                const float rn = rsqrtf(fmaxf(t, 1e-12f));
                h_d[n][0] *= rn; h_d[n][1] *= rn;
                h_d[n][2] *= rn; h_d[n][3] *= rn;
                const int c = c0 + q * 4;
                const unsigned int u0 = pk2(h_d[n][0], h_d[n][1]);
                const unsigned int u1 = pk2(h_d[n][2], h_d[n][3]);
                *reinterpret_cast<uint2*>(hb + (((e << 9) + (c << 1)) ^ bswz))
                    = make_uint2(u0, u1);
            }
        }
    }

    // ---- write back h (fp32) ----
    #pragma unroll
    for (int n = 0; n < 4; ++n)
        *reinterpret_cast<float4v*>(
            out + ((long)b * Ee + n * 16 + sl) * Dd + c0 + q * 4) = h_d[n];
}

extern "C" void kernel_launch(void* const* d_in, const int* in_sizes, int n_in,
                              void* d_out, int out_size, void* d_ws, size_t ws_size,
                              hipStream_t stream) {
    const int*   tok  = (const int*)d_in[0];    // (B,S,L) int32
    const float* mask = (const float*)d_in[1];  // (B,S,L) f32
    const float* keys = (const float*)d_in[2];  // (B,E,D) f32
    const float* emb  = (const float*)d_in[3];  // (VOCAB,D) f32
    const float* U    = (const float*)d_in[4];  // (D,D)
    const float* V    = (const float*)d_in[5];  // (D,D)
    const float* W    = (const float*)d_in[6];  // (D,D)
    float* out = (float*)d_out;

    // workspace layout (floats)
    float* enc = (float*)d_ws;                    // B*S*D      = 2,097,152
    float* kv  = enc + (long)Bb * Ss * Dd;        // B*E*D      = 4,194,304
    float* eW  = kv  + (long)Bb * Ee * Dd;        // B*S*D      = 2,097,152
    float* gkv = eW  + (long)Bb * Ss * Dd;        // B*S*E      =   524,288
    int*   act = (int*)(gkv + (long)Bb * Ss * Ee);// B*S        =     8,192 ints
    unsigned short* Utg = (unsigned short*)(act + Bb * Ss);  // D*D bf16 = 131,072 B

    k_enc<<<Bb * Ss, Dd, 0, stream>>>(tok, mask, emb, enc, act);
    k_rowmat<<<(Bb * Ee) / 16, 256, 0, stream>>>(keys, V, kv);   // kv = keys @ V
    k_rowmat<<<(Bb * Ss) / 16, 256, 0, stream>>>(enc, W, eW);    // eW = enc @ W
    k_gk<<<Bb, 256, 0, stream>>>(enc, keys, gkv);                // gk = dot(enc, keys)
    k_ut<<<Dd / 16, Dd, 0, stream>>>(U, Utg);                    // Utg = bf16(U^T)
    k_scan<<<Bb, 1024, 0, stream>>>(enc, act, gkv, kv, eW, Utg, out);
}

// Round 11
// 399.802 us; speedup vs baseline: 2.1341x; 2.1341x over previous
//
#include <hip/hip_runtime.h>
#include <hip/hip_bf16.h>

// Problem constants (StaticRecurrentEntNet): B=256,S=32,L=32,D=256,E=64,VOCAB=50000
#define Bb 256
#define Ss 32
#define Ll 32
#define Dd 256
#define Ee 64
#define WC_TAIL 224   // U^T rows >= this come from global (L1-resident), not LDS

typedef __attribute__((ext_vector_type(8))) short short8v;
typedef __attribute__((ext_vector_type(4))) float float4v;

static __device__ __forceinline__ unsigned short f2bf(float f) {
    unsigned int x = __float_as_uint(f);
    return (unsigned short)((x + 0x7fffu + ((x >> 16) & 1u)) >> 16);   // RNE
}
static __device__ __forceinline__ unsigned int pk2(float a, float b) {
    return (unsigned int)f2bf(a) | ((unsigned int)f2bf(b) << 16);
}

// ---------------- Kernel A: enc[bs][d] = sum_l emb[tok[bs][l]][d]*mask[bs][l]; active[bs]
__global__ void k_enc(const int* __restrict__ tok, const float* __restrict__ mask,
                      const float* __restrict__ emb, float* __restrict__ enc,
                      int* __restrict__ act) {
    int bs = blockIdx.x;            // 0..B*S-1
    int d  = threadIdx.x;           // 0..255
    const int*   t = tok  + (long)bs * Ll;
    const float* m = mask + (long)bs * Ll;
    float acc = 0.f;
    #pragma unroll 4
    for (int l = 0; l < Ll; ++l) {
        acc += emb[(long)t[l] * Dd + d] * m[l];
    }
    enc[(long)bs * Dd + d] = acc;
    if (d == 0) {
        float s = 0.f;
        for (int l = 0; l < Ll; ++l) s += m[l];
        act[bs] = (s > 0.f) ? 1 : 0;
    }
}

// ---------------- Kernel B: Y[rows][256] = X[rows][256] @ M[256][256]  (fp32)
// 16 rows/block; X staged TRANSPOSED in LDS -> one broadcast b128 read per d
// (replaces 16 scalar b32 reads). Identical FMA order -> bitwise-identical Y.
__global__ void k_rowmat(const float* __restrict__ X, const float* __restrict__ M,
                         float* __restrict__ Y) {
    __shared__ __align__(16) float xs_t[Dd * 16];   // [d][r], 16KB
    int tid = threadIdx.x;
    long row0 = (long)blockIdx.x * 16;
    #pragma unroll
    for (int i = 0; i < 16; ++i) xs_t[tid * 16 + i] = X[(row0 + i) * Dd + tid];
    __syncthreads();
    int cg = tid & 63;   // cols cg*4 .. +3
    int rq = tid >> 6;   // rows rq*4 .. +3
    float acc[4][4];
    #pragma unroll
    for (int r = 0; r < 4; ++r)
        #pragma unroll
        for (int c = 0; c < 4; ++c) acc[r][c] = 0.f;
    for (int d = 0; d < Dd; ++d) {
        float4 mv = *reinterpret_cast<const float4*>(&M[d * Dd + cg * 4]);
        float4 xv = *reinterpret_cast<const float4*>(&xs_t[d * 16 + rq * 4]);
        const float xa[4] = {xv.x, xv.y, xv.z, xv.w};
        #pragma unroll
        for (int r = 0; r < 4; ++r) {
            acc[r][0] += xa[r] * mv.x; acc[r][1] += xa[r] * mv.y;
            acc[r][2] += xa[r] * mv.z; acc[r][3] += xa[r] * mv.w;
        }
    }
    #pragma unroll
    for (int r = 0; r < 4; ++r) {
        float4 o = make_float4(acc[r][0], acc[r][1], acc[r][2], acc[r][3]);
        *reinterpret_cast<float4*>(&Y[(row0 + rq * 4 + r) * Dd + cg * 4]) = o;
    }
}

// ---------------- Kernel Bgk v2: gk[b*32+s][e] = dot(enc[b][s], keys[b][e])
__global__ __launch_bounds__(256) void k_gk(const float* __restrict__ enc,
                                            const float* __restrict__ keys,
                                            float* __restrict__ gk) {
    __shared__ __align__(16) char kls[Ee * 1024];      // keys_b fp32, swizzled, 64KB
    __shared__ __align__(16) float es[Ss * Dd];        // enc_b, 32KB
    const int tid = threadIdx.x;
    const int b   = blockIdx.x;
    {
        const float4* kg = reinterpret_cast<const float4*>(keys + (long)b * Ee * Dd);
        #pragma unroll
        for (int i = 0; i < 16; ++i) {
            const int idx = tid + 256 * i;             // f4 unit, 0..4095
            const int e   = idx >> 6;
            const int d4  = idx & 63;
            *reinterpret_cast<float4*>(kls + (((e << 10) + (d4 << 4)) ^ ((e & 7) << 4)))
                = kg[idx];
        }
        const float4* eg = reinterpret_cast<const float4*>(enc + (long)b * Ss * Dd);
        float4* es4 = reinterpret_cast<float4*>(es);
        #pragma unroll
        for (int i = 0; i < 8; ++i) es4[tid + 256 * i] = eg[tid + 256 * i];
    }
    __syncthreads();
    const int w = tid >> 6;        // wave: s in [w*8, w*8+8)
    const int e = tid & 63;
    float acc[8];
    #pragma unroll
    for (int i = 0; i < 8; ++i) acc[i] = 0.f;
    const char* krow = kls;
    for (int d4 = 0; d4 < 64; ++d4) {
        const float4 kvf = *reinterpret_cast<const float4*>(
            krow + (((e << 10) + (d4 << 4)) ^ ((e & 7) << 4)));
        #pragma unroll
        for (int i = 0; i < 8; ++i) {
            const float4 ev = *reinterpret_cast<const float4*>(&es[(w * 8 + i) * Dd + d4 * 4]);
            acc[i] += ev.x * kvf.x + ev.y * kvf.y + ev.z * kvf.z + ev.w * kvf.w;
        }
    }
    #pragma unroll
    for (int i = 0; i < 8; ++i)
        gk[((long)b * Ss + w * 8 + i) * Ee + e] = acc[i];
}

// ---------------- Kernel Ut: Utg[c][k] = bf16(U[k][c])  (pre-transpose for A-operand)
__global__ void k_ut(const float* __restrict__ U, unsigned short* __restrict__ Utg) {
    const int c0 = blockIdx.x * 16;
    const int k  = threadIdx.x;      // 0..255
    float v[16];
    #pragma unroll
    for (int i = 0; i < 16; ++i) v[i] = U[k * Dd + c0 + i];
    #pragma unroll
    for (int i = 0; i < 16; ++i) Utg[(c0 + i) * Dd + k] = f2bf(v[i]);
}

// ---------------- Kernel D v7: 32-step recurrence. 512 thr = 8 waves (we x wc).
// we = w&1 owns 32 entities (2 e-tiles); wc = w>>2..no: w>>1 owns 64 out-dims (4 mi).
// A = U^T rows from 112KB swizzled LDS (rows >=224 from global, L1-hot).
// B = h e-tiles from 32KB swizzled bf16 mirror hbf (rewritten each step).
// LDS ~146KB -> 1 block/CU -> allocator grants 256 VGPR for 8-wave block
// (measured heuristic: grant = 2048/(waves*blocks_fitting_LDS); rounds 5-10).
// Demand ~180 -> no spill. 2 barriers/step, v3's race-free protocol.
__global__ __launch_bounds__(512, 1) void k_scan(
    const float* __restrict__ enc, const int* __restrict__ act,
    const float* __restrict__ gk,  const float* __restrict__ kv,
    const float* __restrict__ eWm, const unsigned short* __restrict__ Utg,
    float* __restrict__ out) {
    __shared__ __align__(128) unsigned short Uls[WC_TAIL * Dd];  // 112KB [c][k] swz
    __shared__ __align__(128) unsigned short hbf[Ee * Dd];       // 32KB  [e][k] swz
    __shared__ float part_g[4][Ee];                              // 1KB
    __shared__ float part_rn[4][Ee];                             // 1KB

    const int tid = threadIdx.x;
    const int b   = blockIdx.x;
    const int w   = tid >> 6;
    const int l   = tid & 63;
    const int q   = l >> 4;
    const int sl  = l & 15;
    const int we  = w & 1;          // entity-half
    const int wc  = w >> 1;         // out-dim quarter
    const int e0  = we * 32 + sl;   // + n*16
    const int c0  = wc * 64;        // + mi*16 + q*4 + j
    const int bswz = (sl & 7) << 4;

    // ---- zero hbf ----
    {
        uint4 z4 = make_uint4(0u, 0u, 0u, 0u);
        uint4* hz = reinterpret_cast<uint4*>(hbf);
        #pragma unroll
        for (int i = 0; i < 4; ++i) hz[tid + 512 * i] = z4;
    }
    // ---- stage U^T rows [0,224) swizzled ----
    {
        const uint4* g4 = reinterpret_cast<const uint4*>(Utg);
        char* ub = reinterpret_cast<char*>(Uls);
        #pragma unroll
        for (int r = 0; r < 14; ++r) {
            const int u  = tid + 512 * r;          // 16B unit, 0..7167
            const int c  = u >> 5;
            const int kb = (u & 31) << 4;
            *reinterpret_cast<uint4*>(ub + (((c << 9) + kb) ^ ((c & 7) << 4))) = g4[u];
        }
    }

    const unsigned long long actmask = __ballot((l < Ss) && (act[b * Ss + l] != 0));

    float4v h_d[4][2];   // [mi][n]: h[e0+n*16][c0+mi*16+q*4+j]
    #pragma unroll
    for (int mi = 0; mi < 4; ++mi)
        #pragma unroll
        for (int n = 0; n < 2; ++n) h_d[mi][n] = (float4v)0.f;

    const char* ub = reinterpret_cast<const char*>(Uls);
    const char* hc = reinterpret_cast<const char*>(hbf);

    __syncthreads();   // staging + hbf zero visible

#define LDA(KK, A) { _Pragma("unroll") for (int mi_ = 0; mi_ < 4; ++mi_) { \
        const int cc = c0 + mi_ * 16 + sl; \
        if (c0 + mi_ * 16 >= WC_TAIL) \
            A[mi_] = *reinterpret_cast<const short8v*>(Utg + cc * Dd + (KK) * 32 + q * 8); \
        else \
            A[mi_] = *reinterpret_cast<const short8v*>( \
                ub + (((cc << 9) + ((KK) << 6) + (q << 4)) ^ ((sl & 7) << 4))); } }
#define LDB(KK, Bv) { _Pragma("unroll") for (int n_ = 0; n_ < 2; ++n_) { \
        const int ee = e0 + n_ * 16; \
        Bv[n_] = *reinterpret_cast<const short8v*>( \
            hc + (((ee << 9) + ((KK) << 6) + (q << 4)) ^ bswz)); } }
#define MFMA8(A, Bv) { _Pragma("unroll") for (int mi_ = 0; mi_ < 4; ++mi_) \
        _Pragma("unroll") for (int n_ = 0; n_ < 2; ++n_) \
            acc[mi_][n_] = __builtin_amdgcn_mfma_f32_16x16x32_bf16( \
                A[mi_], Bv[n_], acc[mi_][n_], 0, 0, 0); }

    for (int s = 0; s < Ss; ++s) {
        if ((actmask >> s) & 1ull) {
            const long bs = (long)b * Ss + s;
            const float* erow = enc + bs * Dd + c0;
            float4 esc[4];
            #pragma unroll
            for (int mi = 0; mi < 4; ++mi)
                esc[mi] = *reinterpret_cast<const float4*>(erow + mi * 16 + q * 4);
            float gkl[2];
            #pragma unroll
            for (int n = 0; n < 2; ++n) gkl[n] = gk[bs * Ee + e0 + n * 16];

            // ---- g-partials over this wave's 64 d, its 32 e ----
            #pragma unroll
            for (int n = 0; n < 2; ++n) {
                float pg = 0.f;
                #pragma unroll
                for (int mi = 0; mi < 4; ++mi) {
                    pg += esc[mi].x * h_d[mi][n][0] + esc[mi].y * h_d[mi][n][1]
                        + esc[mi].z * h_d[mi][n][2] + esc[mi].w * h_d[mi][n][3];
                }
                pg += __shfl_xor(pg, 16);
                pg += __shfl_xor(pg, 32);
                if (q == 0) part_g[wc][e0 + n * 16] = pg;
            }
            __syncthreads();                                   // B1

            float g2[2];
            #pragma unroll
            for (int n = 0; n < 2; ++n) {
                const int e = e0 + n * 16;
                const float x = (part_g[0][e] + part_g[1][e])
                              + (part_g[2][e] + part_g[3][e]) + gkl[n];
                g2[n] = 1.f / (1.f + expf(-x));
            }

            // ---- GEMM: acc[mi][n] += U^T-rows(A) @ h^T(B), pair-dbuffered ----
            float4v acc[4][2];
            #pragma unroll
            for (int mi = 0; mi < 4; ++mi)
                #pragma unroll
                for (int n = 0; n < 2; ++n) acc[mi][n] = (float4v)0.f;

            short8v A0[4], A1[4], B0[2], B1[2];
            LDA(0, A0); LDB(0, B0);
            #pragma unroll
            for (int kp = 0; kp < 4; ++kp) {
                LDA(2 * kp + 1, A1); LDB(2 * kp + 1, B1);
                MFMA8(A0, B0);
                if (kp < 3) { LDA(2 * kp + 2, A0); LDB(2 * kp + 2, B0); }
                MFMA8(A1, B1);
            }

            // ---- epilogue: h_t = relu(acc+kv+eW); h_d += g*h_t; ss partials ----
            const float* ewrow = eWm + bs * Dd + c0;
            float4 eww[4];
            #pragma unroll
            for (int mi = 0; mi < 4; ++mi)
                eww[mi] = *reinterpret_cast<const float4*>(ewrow + mi * 16 + q * 4);
            float ssp[2] = {0.f, 0.f};
            #pragma unroll
            for (int n = 0; n < 2; ++n) {
                const long krow = ((long)b * Ee + e0 + n * 16) * Dd + c0;
                #pragma unroll
                for (int mi = 0; mi < 4; ++mi) {
                    const float4 kvv = *reinterpret_cast<const float4*>(
                        kv + krow + mi * 16 + q * 4);
                    const float kva[4] = {kvv.x, kvv.y, kvv.z, kvv.w};
                    const float ewa[4] = {eww[mi].x, eww[mi].y, eww[mi].z, eww[mi].w};
                    #pragma unroll
                    for (int j = 0; j < 4; ++j) {
                        float ht = acc[mi][n][j] + kva[j] + ewa[j];
                        ht = fmaxf(ht, 0.f);
                        const float hn = h_d[mi][n][j] + g2[n] * ht;
                        h_d[mi][n][j] = hn;
                        ssp[n] += hn * hn;
                    }
                }
            }
            #pragma unroll
            for (int n = 0; n < 2; ++n) {
                ssp[n] += __shfl_xor(ssp[n], 16);
                ssp[n] += __shfl_xor(ssp[n], 32);
                if (q == 0) part_rn[wc][e0 + n * 16] = ssp[n];
            }
            __syncthreads();                                   // B2

            // ---- normalize + refresh bf16 mirror (this wave's e x d slice) ----
            char* hw = const_cast<char*>(hc);
            #pragma unroll
            for (int n = 0; n < 2; ++n) {
                const int e = e0 + n * 16;
                const float t = (part_rn[0][e] + part_rn[1][e])
                              + (part_rn[2][e] + part_rn[3][e]);
                const float rn = rsqrtf(fmaxf(t, 1e-12f));
                #pragma unroll
                for (int mi = 0; mi < 4; ++mi) {
                    h_d[mi][n][0] *= rn; h_d[mi][n][1] *= rn;
                    h_d[mi][n][2] *= rn; h_d[mi][n][3] *= rn;
                    const int d0 = c0 + mi * 16 + q * 4;
                    const unsigned int u0 = pk2(h_d[mi][n][0], h_d[mi][n][1]);
                    const unsigned int u1 = pk2(h_d[mi][n][2], h_d[mi][n][3]);
                    *reinterpret_cast<uint2*>(hw + (((e << 9) + (d0 << 1)) ^ bswz))
                        = make_uint2(u0, u1);
                }
            }
        }
    }

    // ---- write back h (fp32) ----
    #pragma unroll
    for (int n = 0; n < 2; ++n)
        #pragma unroll
        for (int mi = 0; mi < 4; ++mi) {
            float4 o = make_float4(h_d[mi][n][0], h_d[mi][n][1],
                                   h_d[mi][n][2], h_d[mi][n][3]);
            *reinterpret_cast<float4*>(
                out + ((long)b * Ee + e0 + n * 16) * Dd + c0 + mi * 16 + q * 4) = o;
        }
#undef LDA
#undef LDB
#undef MFMA8
}

extern "C" void kernel_launch(void* const* d_in, const int* in_sizes, int n_in,
                              void* d_out, int out_size, void* d_ws, size_t ws_size,
                              hipStream_t stream) {
    const int*   tok  = (const int*)d_in[0];    // (B,S,L) int32
    const float* mask = (const float*)d_in[1];  // (B,S,L) f32
    const float* keys = (const float*)d_in[2];  // (B,E,D) f32
    const float* emb  = (const float*)d_in[3];  // (VOCAB,D) f32
    const float* U    = (const float*)d_in[4];  // (D,D)
    const float* V    = (const float*)d_in[5];  // (D,D)
    const float* W    = (const float*)d_in[6];  // (D,D)
    float* out = (float*)d_out;

    // workspace layout (floats)
    float* enc = (float*)d_ws;                    // B*S*D      = 2,097,152
    float* kv  = enc + (long)Bb * Ss * Dd;        // B*E*D      = 4,194,304
    float* eW  = kv  + (long)Bb * Ee * Dd;        // B*S*D      = 2,097,152
    float* gkv = eW  + (long)Bb * Ss * Dd;        // B*S*E      =   524,288
    int*   act = (int*)(gkv + (long)Bb * Ss * Ee);// B*S        =     8,192 ints
    unsigned short* Utg = (unsigned short*)(act + Bb * Ss);  // D*D bf16 = 131,072 B

    k_enc<<<Bb * Ss, Dd, 0, stream>>>(tok, mask, emb, enc, act);
    k_rowmat<<<(Bb * Ee) / 16, 256, 0, stream>>>(keys, V, kv);   // kv = keys @ V
    k_rowmat<<<(Bb * Ss) / 16, 256, 0, stream>>>(enc, W, eW);    // eW = enc @ W
    k_gk<<<Bb, 256, 0, stream>>>(enc, keys, gkv);                // gk = dot(enc, keys)
    k_ut<<<Dd / 16, Dd, 0, stream>>>(U, Utg);                    // Utg = bf16(U^T)
    k_scan<<<Bb, 512, 0, stream>>>(enc, act, gkv, kv, eW, Utg, out);
}